// Round 1
// baseline (458.936 us; speedup 1.0000x reference)
//
#include <hip/hip_runtime.h>

#define B_   16
#define CIN  128
#define COUT 128
#define SD   512
#define H_   128
#define W_   128

typedef __bf16 bf16x8  __attribute__((ext_vector_type(8)));
typedef float floatx16 __attribute__((ext_vector_type(16)));

// ---------- kernel A: style[b][c] = (sv[b]*1/sqrt(512)) . proj_w[c] + proj_b[c]
__global__ void style_kernel(const float* __restrict__ sv, const float* __restrict__ pw,
                             const float* __restrict__ pb, float* __restrict__ style) {
    int bid = blockIdx.x;
    int b = bid >> 7, c = bid & 127;
    int lane = threadIdx.x;
    const float* svb = sv + b * SD;
    const float* pwc = pw + (size_t)c * SD;
    float s = 0.f;
#pragma unroll
    for (int i = 0; i < SD; i += 64) s += svb[i + lane] * pwc[i + lane];
#pragma unroll
    for (int off = 32; off > 0; off >>= 1) s += __shfl_down(s, off, 64);
    if (lane == 0) style[b * CIN + c] = s * 0.044194173824159216f + pb[c];
}

// ---------- kernel B: modulate + demod, emit bf16 in [b][tap][chunk][o][c16] layout
__global__ void modw_kernel(const float* __restrict__ weight, const float* __restrict__ style,
                            __bf16* __restrict__ wmod) {
    int bid = blockIdx.x;
    int b = bid >> 7, o = bid & 127;
    int c = threadIdx.x;  // 0..127
    float s = style[b * CIN + c];
    const float* wp = weight + ((size_t)o * CIN + c) * 9;
    float v[9];
    float ss = 0.f;
#pragma unroll
    for (int t = 0; t < 9; ++t) { v[t] = wp[t] * s; ss += v[t] * v[t]; }
#pragma unroll
    for (int off = 32; off > 0; off >>= 1) ss += __shfl_down(ss, off, 64);
    __shared__ float sh[2];
    int wid = c >> 6, lane = c & 63;
    if (lane == 0) sh[wid] = ss;
    __syncthreads();
    float d = rsqrtf(sh[0] + sh[1] + 1e-8f);
    int chunk = c >> 4, ci = c & 15;
#pragma unroll
    for (int t = 0; t < 9; ++t) {
        wmod[(((((size_t)b * 9 + t) * 8 + chunk) * 128 + o) * 16 + ci)] = (__bf16)(v[t] * d);
    }
}

// ---------- kernel C: implicit-GEMM conv, one block = [o 0..127] x [2 rows x 128 w]
#define CH 16
#define WX 130
__global__ __launch_bounds__(256, 2)
void conv_kernel(const float* __restrict__ x, const __bf16* __restrict__ wmod,
                 float* __restrict__ out) {
    __shared__ __align__(16) __bf16 Xs[4 * WX * CH];  // 16640 B
    int b  = blockIdx.y;
    int h0 = blockIdx.x * 2;
    int tid = threadIdx.x;
    int wv = tid >> 6, lane = tid & 63;
    int n = lane & 31, hf = lane >> 5;
    int obase = (wv & 1) * 64;  // this wave's 2 o-tiles: obase, obase+32
    int r = wv >> 1;            // this wave's output row within the pair

    floatx16 acc[2][4];
#pragma unroll
    for (int i = 0; i < 2; ++i)
#pragma unroll
        for (int j = 0; j < 4; ++j)
#pragma unroll
            for (int k = 0; k < 16; ++k) acc[i][j][k] = 0.f;

    const float* xb = x + (size_t)b * CIN * H_ * W_;

    for (int ch = 0; ch < 8; ++ch) {
        int cbase = ch * CH;
        // stage x[b, cbase:cbase+16, h0-1:h0+3, -1:129] -> LDS bf16 [row][w'][c16] (xor-swizzled)
        for (int idx = tid; idx < 4 * WX * CH; idx += 256) {
            int c    = idx & 15;
            int rest = idx >> 4;
            int wp   = rest % WX;
            int row  = rest / WX;
            int hh = h0 - 1 + row;
            int ww = wp - 1;
            float val = 0.f;
            if (hh >= 0 && hh < H_ && ww >= 0 && ww < W_)
                val = xb[((size_t)(cbase + c) * H_ + hh) * W_ + ww];
            int cg = c >> 3;
            int phys = (row * WX + wp) * CH + ((cg ^ (wp & 1)) << 3) + (c & 7);
            Xs[phys] = (__bf16)val;
        }
        __syncthreads();

#pragma unroll
        for (int tap = 0; tap < 9; ++tap) {
            int kh = tap / 3, kw = tap % 3;
            // A fragments straight from global (L2-hot), coalesced 16B/lane
            const __bf16* ap = wmod +
                (((((size_t)b * 9 + tap) * 8 + ch) * 128 + obase + n) * 16 + hf * 8);
            bf16x8 a0 = *(const bf16x8*)ap;
            bf16x8 a1 = *(const bf16x8*)(ap + 32 * 16);
            int row = r + kh;
#pragma unroll
            for (int wt = 0; wt < 4; ++wt) {
                int wp = wt * 32 + n + kw;  // stored w' = w+1, so this is x-col (w0+n+kw-1)
                int phys = (row * WX + wp) * CH + ((hf ^ (wp & 1)) << 3);
                bf16x8 bfrag = *(const bf16x8*)&Xs[phys];
                acc[0][wt] = __builtin_amdgcn_mfma_f32_32x32x16_bf16(a0, bfrag, acc[0][wt], 0, 0, 0);
                acc[1][wt] = __builtin_amdgcn_mfma_f32_32x32x16_bf16(a1, bfrag, acc[1][wt], 0, 0, 0);
            }
        }
        __syncthreads();
    }

    // epilogue: C/D layout col=lane&31, row=(reg&3)+8*(reg>>2)+4*(lane>>5)
    float* ob = out + ((size_t)(b * COUT) * H_ + (h0 + r)) * W_;
#pragma unroll
    for (int i = 0; i < 2; ++i) {
#pragma unroll
        for (int reg = 0; reg < 16; ++reg) {
            int o = obase + i * 32 + (reg & 3) + 8 * (reg >> 2) + 4 * hf;
#pragma unroll
            for (int wt = 0; wt < 4; ++wt)
                ob[(size_t)o * (H_ * W_) + wt * 32 + n] = acc[i][wt][reg];
        }
    }
}

extern "C" void kernel_launch(void* const* d_in, const int* in_sizes, int n_in,
                              void* d_out, int out_size, void* d_ws, size_t ws_size,
                              hipStream_t stream) {
    const float* x      = (const float*)d_in[0];
    const float* sv     = (const float*)d_in[1];
    const float* pw     = (const float*)d_in[2];
    const float* pb     = (const float*)d_in[3];
    const float* weight = (const float*)d_in[4];
    float* out = (float*)d_out;

    float*  style = (float*)d_ws;                      // 16*128*4 = 8 KB
    __bf16* wmod  = (__bf16*)((char*)d_ws + 8192);     // 16*9*8*128*16*2 = 4.72 MB

    style_kernel<<<B_ * CIN, 64, 0, stream>>>(sv, pw, pb, style);
    modw_kernel<<<B_ * COUT, 128, 0, stream>>>(weight, style, wmod);
    conv_kernel<<<dim3(H_ / 2, B_), 256, 0, stream>>>(x, wmod, out);
}

// Round 2
// 344.486 us; speedup vs baseline: 1.3322x; 1.3322x over previous
//
#include <hip/hip_runtime.h>
#include <cstdint>

#define B_   16
#define CIN  128
#define COUT 128
#define SD   512
#define H_   128
#define W_   128

typedef __bf16 bf16x8  __attribute__((ext_vector_type(8)));
typedef float  floatx4 __attribute__((ext_vector_type(4)));
typedef float floatx16 __attribute__((ext_vector_type(16)));

// ---------- kernel A: style[b][c] = (sv[b]/sqrt(512)) . proj_w[c] + proj_b[c]
__global__ void style_kernel(const float* __restrict__ sv, const float* __restrict__ pw,
                             const float* __restrict__ pb, float* __restrict__ style) {
    int bid = blockIdx.x;
    int b = bid >> 7, c = bid & 127;
    int lane = threadIdx.x;
    const float* svb = sv + b * SD;
    const float* pwc = pw + (size_t)c * SD;
    float s = 0.f;
#pragma unroll
    for (int i = 0; i < SD; i += 64) s += svb[i + lane] * pwc[i + lane];
#pragma unroll
    for (int off = 32; off > 0; off >>= 1) s += __shfl_down(s, off, 64);
    if (lane == 0) style[b * CIN + c] = s * 0.044194173824159216f + pb[c];
}

// ---------- kernel B: modulate + demod, emit bf16 in [b][tap][chunk][o][c16] layout
__global__ void modw_kernel(const float* __restrict__ weight, const float* __restrict__ style,
                            __bf16* __restrict__ wmod) {
    int bid = blockIdx.x;
    int b = bid >> 7, o = bid & 127;
    int c = threadIdx.x;  // 0..127
    float s = style[b * CIN + c];
    const float* wp = weight + ((size_t)o * CIN + c) * 9;
    float v[9];
    float ss = 0.f;
#pragma unroll
    for (int t = 0; t < 9; ++t) { v[t] = wp[t] * s; ss += v[t] * v[t]; }
#pragma unroll
    for (int off = 32; off > 0; off >>= 1) ss += __shfl_down(ss, off, 64);
    __shared__ float sh[2];
    int wid = c >> 6, lane = c & 63;
    if (lane == 0) sh[wid] = ss;
    __syncthreads();
    float d = rsqrtf(sh[0] + sh[1] + 1e-8f);
    int chunk = c >> 4, ci = c & 15;
#pragma unroll
    for (int t = 0; t < 9; ++t) {
        wmod[(((((size_t)b * 9 + t) * 8 + chunk) * 128 + o) * 16 + ci)] = (__bf16)(v[t] * d);
    }
}

// ---------- kernel T: x fp32 [b][c][h][w] -> xT bf16 [b][chunk8][h][w][c16]
__global__ __launch_bounds__(256)
void xpose_kernel(const float* __restrict__ x, __bf16* __restrict__ xT) {
    int ch = blockIdx.x;   // 0..7  (c16 chunk)
    int hq = blockIdx.y;   // 0..15 (8 rows each)
    int b  = blockIdx.z;
    int t  = threadIdx.x;
    int wq = t & 31;       // w-quad
    int cp = t >> 5;       // c-pair 0..7
    int c0 = ch * 16 + cp * 2;
    const float* xa = x + (((size_t)b * CIN + c0    ) * H_ + hq * 8) * W_ + wq * 4;
    const float* xc = x + (((size_t)b * CIN + c0 + 1) * H_ + hq * 8) * W_ + wq * 4;
    uint32_t* dst = (uint32_t*)xT + ((((size_t)b * 8 + ch) * H_ + hq * 8) * W_) * 8 + cp;
#pragma unroll
    for (int hr = 0; hr < 8; ++hr) {
        floatx4 a  = *(const floatx4*)(xa + (size_t)hr * W_);
        floatx4 b2 = *(const floatx4*)(xc + (size_t)hr * W_);
#pragma unroll
        for (int j = 0; j < 4; ++j) {
            unsigned short lo = __builtin_bit_cast(unsigned short, (__bf16)a[j]);
            unsigned short hi = __builtin_bit_cast(unsigned short, (__bf16)b2[j]);
            dst[(size_t)hr * W_ * 8 + (size_t)(wq * 4 + j) * 8] =
                (uint32_t)lo | ((uint32_t)hi << 16);
        }
    }
}

// ---------- kernel C: implicit-GEMM conv
// block = o[0..127] x rows {h0,h0+1} x w[w0..w0+63]; 4 waves, 64 acc regs/wave
#define WXT 66
__global__ __launch_bounds__(256, 4)
void conv_kernel(const __bf16* __restrict__ xT, const __bf16* __restrict__ wmod,
                 float* __restrict__ out) {
    __shared__ __align__(16) __bf16 Xs[4 * WXT * 16];  // 8448 B
    int w0 = blockIdx.x * 64;   // 0..1
    int h0 = blockIdx.y * 2;    // 0..63
    int b  = blockIdx.z;
    int tid = threadIdx.x;
    int wv = tid >> 6, lane = tid & 63;
    int n = lane & 31, hf = lane >> 5;
    int obase = (wv & 1) * 64;  // wave's 2 o-tiles: obase, obase+32
    int r = wv >> 1;            // wave's output row within the pair

    floatx16 acc[2][2];
#pragma unroll
    for (int i = 0; i < 2; ++i)
#pragma unroll
        for (int j = 0; j < 2; ++j)
#pragma unroll
            for (int k = 0; k < 16; ++k) acc[i][j][k] = 0.f;

    const __bf16* xb = xT + (size_t)b * 8 * H_ * W_ * 16;

    for (int ch = 0; ch < 8; ++ch) {
        __syncthreads();
        // stage xT[b,ch, h0-1..h0+2, w0-1..w0+64, 0..15] -> Xs[row][wp][c16]
        for (int idx = tid; idx < 4 * WXT * 2; idx += 256) {  // 528 16B granules
            int row = idx / (WXT * 2);
            int rem = idx - row * (WXT * 2);
            int wp = rem >> 1, g = rem & 1;
            int hh = h0 - 1 + row, ww = w0 - 1 + wp;
            bf16x8 v;
#pragma unroll
            for (int k = 0; k < 8; ++k) v[k] = (__bf16)0.f;
            if ((unsigned)hh < (unsigned)H_ && (unsigned)ww < (unsigned)W_)
                v = *(const bf16x8*)(xb + ((((size_t)ch * H_ + hh) * W_ + ww) * 16) + g * 8);
            *(bf16x8*)(&Xs[(size_t)idx * 8]) = v;
        }
        __syncthreads();

#pragma unroll
        for (int tap = 0; tap < 9; ++tap) {
            int kh = tap / 3, kw = tap % 3;
            const __bf16* ap = wmod +
                (((((size_t)b * 9 + tap) * 8 + ch) * 128 + obase + n) * 16 + hf * 8);
            bf16x8 a0 = *(const bf16x8*)ap;
            bf16x8 a1 = *(const bf16x8*)(ap + 32 * 16);
            int row = r + kh;
#pragma unroll
            for (int wt = 0; wt < 2; ++wt) {
                int wp = wt * 32 + n + kw;
                bf16x8 bfrag = *(const bf16x8*)(&Xs[(row * WXT + wp) * 16 + hf * 8]);
                acc[0][wt] = __builtin_amdgcn_mfma_f32_32x32x16_bf16(a0, bfrag, acc[0][wt], 0, 0, 0);
                acc[1][wt] = __builtin_amdgcn_mfma_f32_32x32x16_bf16(a1, bfrag, acc[1][wt], 0, 0, 0);
            }
        }
    }

    // epilogue: C/D layout col=lane&31, row=(reg&3)+8*(reg>>2)+4*(lane>>5)
    float* ob = out + (((size_t)b * COUT) * H_ + (h0 + r)) * W_ + w0;
#pragma unroll
    for (int i = 0; i < 2; ++i) {
#pragma unroll
        for (int reg = 0; reg < 16; ++reg) {
            int o = obase + i * 32 + (reg & 3) + 8 * (reg >> 2) + 4 * hf;
#pragma unroll
            for (int wt = 0; wt < 2; ++wt)
                ob[(size_t)o * (H_ * W_) + wt * 32 + n] = acc[i][wt][reg];
        }
    }
}

extern "C" void kernel_launch(void* const* d_in, const int* in_sizes, int n_in,
                              void* d_out, int out_size, void* d_ws, size_t ws_size,
                              hipStream_t stream) {
    const float* x      = (const float*)d_in[0];
    const float* sv     = (const float*)d_in[1];
    const float* pw     = (const float*)d_in[2];
    const float* pb     = (const float*)d_in[3];
    const float* weight = (const float*)d_in[4];
    float* out = (float*)d_out;

    float*  style = (float*)d_ws;                          // 8 KB
    __bf16* wmod  = (__bf16*)((char*)d_ws + 8192);         // 4.72 MB
    __bf16* xT    = (__bf16*)((char*)d_ws + 8192 + 4718592); // 67.1 MB

    style_kernel<<<B_ * CIN, 64, 0, stream>>>(sv, pw, pb, style);
    modw_kernel<<<B_ * COUT, 128, 0, stream>>>(weight, style, wmod);
    xpose_kernel<<<dim3(8, 16, B_), 256, 0, stream>>>(x, xT);
    conv_kernel<<<dim3(2, 64, B_), 256, 0, stream>>>(xT, wmod, out);
}

// Round 3
// 308.853 us; speedup vs baseline: 1.4859x; 1.1154x over previous
//
#include <hip/hip_runtime.h>
#include <cstdint>

#define B_   16
#define CIN  128
#define COUT 128
#define SD   512
#define H_   128
#define W_   128

typedef __bf16 bf16x8  __attribute__((ext_vector_type(8)));
typedef float  floatx4 __attribute__((ext_vector_type(4)));
typedef float floatx16 __attribute__((ext_vector_type(16)));

// ---------- kernel A: style[b][c] = (sv[b]/sqrt(512)) . proj_w[c] + proj_b[c]
__global__ void style_kernel(const float* __restrict__ sv, const float* __restrict__ pw,
                             const float* __restrict__ pb, float* __restrict__ style) {
    int bid = blockIdx.x;
    int b = bid >> 7, c = bid & 127;
    int lane = threadIdx.x;
    const float* svb = sv + b * SD;
    const float* pwc = pw + (size_t)c * SD;
    float s = 0.f;
#pragma unroll
    for (int i = 0; i < SD; i += 64) s += svb[i + lane] * pwc[i + lane];
#pragma unroll
    for (int off = 32; off > 0; off >>= 1) s += __shfl_down(s, off, 64);
    if (lane == 0) style[b * CIN + c] = s * 0.044194173824159216f + pb[c];
}

// ---------- kernel B: modulate + demod, emit bf16 in [b][tap][chunk][o][c16] layout
__global__ void modw_kernel(const float* __restrict__ weight, const float* __restrict__ style,
                            __bf16* __restrict__ wmod) {
    int bid = blockIdx.x;
    int b = bid >> 7, o = bid & 127;
    int c = threadIdx.x;  // 0..127
    float s = style[b * CIN + c];
    const float* wp = weight + ((size_t)o * CIN + c) * 9;
    float v[9];
    float ss = 0.f;
#pragma unroll
    for (int t = 0; t < 9; ++t) { v[t] = wp[t] * s; ss += v[t] * v[t]; }
#pragma unroll
    for (int off = 32; off > 0; off >>= 1) ss += __shfl_down(ss, off, 64);
    __shared__ float sh[2];
    int wid = c >> 6, lane = c & 63;
    if (lane == 0) sh[wid] = ss;
    __syncthreads();
    float d = rsqrtf(sh[0] + sh[1] + 1e-8f);
    int chunk = c >> 4, ci = c & 15;
#pragma unroll
    for (int t = 0; t < 9; ++t) {
        wmod[(((((size_t)b * 9 + t) * 8 + chunk) * 128 + o) * 16 + ci)] = (__bf16)(v[t] * d);
    }
}

// ---------- kernel T: x fp32 [b][c][h][w] -> xT bf16 [b][chunk8][h][w][c16]
// LDS transpose: coalesced float4 loads, bank-safe LDS, coalesced uint2 stores.
__global__ __launch_bounds__(256)
void xpose_kernel(const float* __restrict__ x, __bf16* __restrict__ xT) {
    // block: (ch, hq, b); covers 16 c x 4 rows x 128 w
    __shared__ uint32_t T[4 * 4 * 8 * 32];  // [hr][w&3][cp][w>>2] = 4096 words, 16 KB
    int ch = blockIdx.x;   // 0..7
    int hq = blockIdx.y;   // 0..31 (4 rows each)
    int b  = blockIdx.z;
    int t  = threadIdx.x;
    int cp = t >> 5;       // c-pair 0..7
    int wq = t & 31;       // w-quad 0..31
    int c0 = ch * 16 + cp * 2;
    const float* pa = x + (((size_t)b * CIN + c0    ) * H_ + hq * 4) * W_ + wq * 4;
    const float* pc = x + (((size_t)b * CIN + c0 + 1) * H_ + hq * 4) * W_ + wq * 4;
#pragma unroll
    for (int hr = 0; hr < 4; ++hr) {
        floatx4 va = *(const floatx4*)(pa + (size_t)hr * W_);
        floatx4 vb = *(const floatx4*)(pc + (size_t)hr * W_);
#pragma unroll
        for (int j = 0; j < 4; ++j) {
            uint32_t lo = (uint32_t)__builtin_bit_cast(unsigned short, (__bf16)va[j]);
            uint32_t hi = (uint32_t)__builtin_bit_cast(unsigned short, (__bf16)vb[j]);
            // w = wq*4+j; bank = wq -> 2-way (cp parity) = free
            T[((hr * 4 + j) * 8 + cp) * 32 + wq] = lo | (hi << 16);
        }
    }
    __syncthreads();
    // phase 2: out flat word o = (hr*128 + w)*8 + cpair, fully coalesced uint2 stores
    uint32_t* dst = (uint32_t*)xT + ((((size_t)b * 8 + ch) * H_ + hq * 4) * W_) * 8;
#pragma unroll
    for (int it = 0; it < 8; ++it) {
        int o0 = it * 512 + t * 2;
        int cpr = o0 & 7;             // even
        int w   = (o0 >> 3) & 127;
        int hr  = o0 >> 10;
        int base = ((hr * 4 + (w & 3)) * 8);
        uint32_t v0 = T[(base + cpr    ) * 32 + (w >> 2)];
        uint32_t v1 = T[(base + cpr + 1) * 32 + (w >> 2)];
        uint2 pk; pk.x = v0; pk.y = v1;
        *(uint2*)(dst + o0) = pk;
    }
}

// ---------- kernel C: implicit-GEMM conv
// block = o[0..127] x rows {h0,h0+1} x w[w0..w0+63]; 4 waves; A hoisted, LDS dbuf
#define WXT 66
__global__ __launch_bounds__(256, 2)
void conv_kernel(const __bf16* __restrict__ xT, const __bf16* __restrict__ wmod,
                 float* __restrict__ out) {
    __shared__ __align__(16) __bf16 Xs[2][4 * WXT * 16];  // 2 x 8448 B
    int w0 = blockIdx.x * 64;
    int h0 = blockIdx.y * 2;
    int b  = blockIdx.z;
    int tid = threadIdx.x;
    int wv = tid >> 6, lane = tid & 63;
    int n = lane & 31, hf = lane >> 5;
    int obase = (wv & 1) * 64;
    int r = wv >> 1;

    floatx16 acc[2][2];
#pragma unroll
    for (int i = 0; i < 2; ++i)
#pragma unroll
        for (int j = 0; j < 2; ++j)
#pragma unroll
            for (int k = 0; k < 16; ++k) acc[i][j][k] = 0.f;

    const __bf16* xb = xT + (size_t)b * 8 * H_ * W_ * 16;

    // staging slot precompute: 528 granules (8 bf16 each) = 4 rows x 66 wp x 2 g
    bool sact[3], sval[3];
    const __bf16* sptr[3];
    int soff[3];
#pragma unroll
    for (int s = 0; s < 3; ++s) {
        int idx = tid + s * 256;
        bool act = (s < 2) || (tid < 16);
        int row = idx / 132;
        int rem = idx - row * 132;
        int wp = rem >> 1, g = rem & 1;
        int hh = h0 - 1 + row, ww = w0 - 1 + wp;
        sact[s] = act;
        sval[s] = act && (unsigned)hh < (unsigned)H_ && (unsigned)ww < (unsigned)W_;
        sptr[s] = xb + ((size_t)hh * W_ + ww) * 16 + g * 8;
        soff[s] = idx * 8;
    }

    bf16x8 sv[3];
#pragma unroll
    for (int s = 0; s < 3; ++s) {
#pragma unroll
        for (int k = 0; k < 8; ++k) sv[s][k] = (__bf16)0.f;
        if (sval[s]) sv[s] = *(const bf16x8*)(sptr[s]);   // chunk 0
    }

    const __bf16* apb = wmod + ((((size_t)b * 9) * 8) * 128 + obase + n) * 16 + hf * 8;
    // strides (elems): tap: 8*128*16=16384, ch: 128*16=2048, o+32: 512

    for (int ch = 0; ch < 8; ++ch) {
        // 1) hoist all A-fragment loads for this chunk (18 b128, stay in flight)
        bf16x8 a[9][2];
#pragma unroll
        for (int tap = 0; tap < 9; ++tap) {
            const __bf16* ap = apb + tap * 16384 + ch * 2048;
            a[tap][0] = *(const bf16x8*)ap;
            a[tap][1] = *(const bf16x8*)(ap + 512);
        }
        // 2) write prefetched staging regs to this chunk's LDS buffer
        __bf16* xbuf = Xs[ch & 1];
#pragma unroll
        for (int s = 0; s < 3; ++s)
            if (sact[s]) *(bf16x8*)(xbuf + soff[s]) = sv[s];
        // 3) prefetch next chunk's staging into regs (issued after A-loads -> newer)
        if (ch < 7) {
#pragma unroll
            for (int s = 0; s < 3; ++s) {
#pragma unroll
                for (int k = 0; k < 8; ++k) sv[s][k] = (__bf16)0.f;
                if (sval[s]) sv[s] = *(const bf16x8*)(sptr[s] + (size_t)(ch + 1) * (H_ * W_ * 16));
            }
        }
        // 4) single barrier per chunk (double buffer makes 2nd barrier unnecessary:
        //    writer of buf k in iter k+2 must pass barrier k+1, after all iter-k reads)
        __syncthreads();
        // 5) compute: pure LDS reads + MFMA, A from registers
#pragma unroll
        for (int tap = 0; tap < 9; ++tap) {
            int kh = tap / 3, kw = tap % 3;
            int row = r + kh;
#pragma unroll
            for (int wt = 0; wt < 2; ++wt) {
                int wp = wt * 32 + n + kw;
                bf16x8 bfrag = *(const bf16x8*)(xbuf + (row * WXT + wp) * 16 + hf * 8);
                acc[0][wt] = __builtin_amdgcn_mfma_f32_32x32x16_bf16(a[tap][0], bfrag, acc[0][wt], 0, 0, 0);
                acc[1][wt] = __builtin_amdgcn_mfma_f32_32x32x16_bf16(a[tap][1], bfrag, acc[1][wt], 0, 0, 0);
            }
        }
    }

    // epilogue: C/D layout col=lane&31, row=(reg&3)+8*(reg>>2)+4*(lane>>5)
    float* ob = out + (((size_t)b * COUT) * H_ + (h0 + r)) * W_ + w0;
#pragma unroll
    for (int i = 0; i < 2; ++i) {
#pragma unroll
        for (int reg = 0; reg < 16; ++reg) {
            int o = obase + i * 32 + (reg & 3) + 8 * (reg >> 2) + 4 * hf;
#pragma unroll
            for (int wt = 0; wt < 2; ++wt)
                __builtin_nontemporal_store(acc[i][wt][reg],
                    &ob[(size_t)o * (H_ * W_) + wt * 32 + n]);
        }
    }
}

extern "C" void kernel_launch(void* const* d_in, const int* in_sizes, int n_in,
                              void* d_out, int out_size, void* d_ws, size_t ws_size,
                              hipStream_t stream) {
    const float* x      = (const float*)d_in[0];
    const float* sv     = (const float*)d_in[1];
    const float* pw     = (const float*)d_in[2];
    const float* pb     = (const float*)d_in[3];
    const float* weight = (const float*)d_in[4];
    float* out = (float*)d_out;

    float*  style = (float*)d_ws;                            // 8 KB
    __bf16* wmod  = (__bf16*)((char*)d_ws + 8192);           // 4.72 MB
    __bf16* xT    = (__bf16*)((char*)d_ws + 8192 + 4718592); // 67.1 MB

    style_kernel<<<B_ * CIN, 64, 0, stream>>>(sv, pw, pb, style);
    modw_kernel<<<B_ * COUT, 128, 0, stream>>>(weight, style, wmod);
    xpose_kernel<<<dim3(8, 32, B_), 256, 0, stream>>>(x, xT);
    conv_kernel<<<dim3(2, 64, B_), 256, 0, stream>>>(xT, wmod, out);
}